// Round 1
// baseline (676.656 us; speedup 1.0000x reference)
//
#include <hip/hip_runtime.h>
#include <hip/hip_bf16.h>
#include <cstdint>
#include <cstddef>

typedef unsigned short u16;
typedef __attribute__((ext_vector_type(8))) short bf16x8;
typedef __attribute__((ext_vector_type(4))) float f32x4;

#define MFMA16(a,b,c) __builtin_amdgcn_mfma_f32_16x16x32_bf16(a,b,c,0,0,0)

static constexpr int kB = 8, kH = 12, kN = 1025, kC = 768, kD = 64;
static constexpr int kBH = kB*kH;          // 96
static constexpr int kNP = 1056;           // padded N (33*32)
static constexpr int kM  = kB*kN;          // 8200
static constexpr float kScale = 0.125f;

__device__ __forceinline__ u16 f2b(float f){
  unsigned u = __builtin_bit_cast(unsigned, f);
  u = (u + 0x7fffu + ((u>>16)&1u)) >> 16;
  return (u16)u;
}
__device__ __forceinline__ float b2f(u16 s){
  unsigned u = ((unsigned)s)<<16;
  return __builtin_bit_cast(float, u);
}

// ---------------- conversions ----------------
__global__ void k_conv_x(const float4* __restrict__ x, u16* __restrict__ out, int n4){
  int i = blockIdx.x*blockDim.x + threadIdx.x;
  int stride = gridDim.x*blockDim.x;
  for (; i<n4; i+=stride){
    float4 v = x[i];
    ushort4 o;
    o.x=f2b(v.x); o.y=f2b(v.y); o.z=f2b(v.z); o.w=f2b(v.w);
    *reinterpret_cast<ushort4*>(out + (size_t)i*4) = o;
  }
}

__global__ void k_conv_w(const float* __restrict__ w0, const float* __restrict__ w1,
                         const float* __restrict__ w2, const float* __restrict__ w3,
                         u16* __restrict__ out){
  const float* ws[4] = {w0,w1,w2,w3};
  int sel = blockIdx.y;
  const float4* src = reinterpret_cast<const float4*>(ws[sel]);
  int i = blockIdx.x*blockDim.x + threadIdx.x;   // 0..147455
  float4 v = src[i];
  ushort4 o;
  o.x=f2b(v.x); o.y=f2b(v.y); o.z=f2b(v.z); o.w=f2b(v.w);
  *reinterpret_cast<ushort4*>(out + (size_t)sel*589824 + (size_t)i*4) = o;
}

// mask may arrive as bool8 / int32 / float32 — detect via nonzero-byte density.
__global__ void k_mask(const unsigned char* __restrict__ m, int* __restrict__ out, int n){
  __shared__ int cnt;
  if (threadIdx.x==0) cnt = 0;
  __syncthreads();
  int local = 0;
  for (int i=threadIdx.x; i<1024; i+=blockDim.x) local += (m[i]!=0);
  atomicAdd(&cnt, local);
  __syncthreads();
  bool b8 = (cnt > 512);   // bool8 w/ ~90% ones -> ~922; int32 -> ~230; f32 -> ~461
  for (int i=threadIdx.x; i<n; i+=blockDim.x){
    int v = b8 ? (m[i]!=0) : (reinterpret_cast<const int*>(m)[i] != 0);
    out[i] = v;
  }
}

// ---------------- QKV GEMM ----------------
// C[m][J] = sum_c x[m][c] * W_sel[j][c];  writes bf16 to qkv[sel][(b*12+h)][n][d]
__global__ __launch_bounds__(256) void k_gemm_qkv(const u16* __restrict__ xb,
                                                  const u16* __restrict__ wb,
                                                  u16* __restrict__ qkv){
  __shared__ u16 As[64][40];
  __shared__ u16 Bs[64][40];
  const int m0 = blockIdx.x*64;
  const int J0 = blockIdx.y*64;
  const int sel = J0/768;
  const int jb  = J0%768;
  const u16* W = wb + (size_t)sel*589824;
  const int t = threadIdx.x;
  const int lr = t>>2, lc=(t&3)*8;
  const int wave=t>>6, lane=t&63;
  const int wr=(wave>>1)*32, wc=(wave&1)*32;
  const int g=lane>>4, cl=lane&15;
  f32x4 acc[2][2];
  #pragma unroll
  for (int fm=0;fm<2;fm++)
    #pragma unroll
    for (int fn=0;fn<2;fn++) acc[fm][fn] = (f32x4){0.f,0.f,0.f,0.f};

  for (int k0=0; k0<768; k0+=32){
    __syncthreads();
    uint4 av = {0u,0u,0u,0u};
    int gm = m0 + lr;
    if (gm < kM) av = *reinterpret_cast<const uint4*>(xb + (size_t)gm*768 + k0 + lc);
    *reinterpret_cast<uint4*>(&As[lr][lc]) = av;
    uint4 bv = *reinterpret_cast<const uint4*>(W + (size_t)(jb+lr)*768 + k0 + lc);
    *reinterpret_cast<uint4*>(&Bs[lr][lc]) = bv;
    __syncthreads();
    bf16x8 a0 = *reinterpret_cast<const bf16x8*>(&As[wr+cl][g*8]);
    bf16x8 a1 = *reinterpret_cast<const bf16x8*>(&As[wr+16+cl][g*8]);
    bf16x8 b0 = *reinterpret_cast<const bf16x8*>(&Bs[wc+cl][g*8]);
    bf16x8 b1 = *reinterpret_cast<const bf16x8*>(&Bs[wc+16+cl][g*8]);
    acc[0][0] = MFMA16(a0,b0,acc[0][0]);
    acc[0][1] = MFMA16(a0,b1,acc[0][1]);
    acc[1][0] = MFMA16(a1,b0,acc[1][0]);
    acc[1][1] = MFMA16(a1,b1,acc[1][1]);
  }
  #pragma unroll
  for (int fm=0;fm<2;fm++){
    #pragma unroll
    for (int fn=0;fn<2;fn++){
      #pragma unroll
      for (int i=0;i<4;i++){
        int gm = m0 + wr + fm*16 + g*4 + i;
        if (gm >= kM) continue;
        int gc = jb + wc + fn*16 + cl;       // col within 768
        int b = gm/1025, n = gm - b*1025;
        int h = gc>>6, dd = gc&63;
        qkv[(size_t)sel*6297600 + (((size_t)(b*12+h))*1025 + n)*64 + dd] = f2b(acc[fm][fn][i]);
      }
    }
  }
}

// ---------------- depthwise pool + layernorm ----------------
// one wave per token; lane = channel d. transposed=1 writes [d][np] (for V).
__global__ __launch_bounds__(256) void k_pool(const u16* __restrict__ in, const float* __restrict__ w9,
    const float* __restrict__ gg, const float* __restrict__ bb2, u16* __restrict__ out, int transposed){
  const int wave = threadIdx.x>>6, d = threadIdx.x&63;
  const int grp = blockIdx.x % 264;
  const int bh  = blockIdx.x / 264;
  const int np  = grp*4 + wave;
  float v = 0.f;
  if (np < kN){
    const u16* base = in + (size_t)bh*kN*kD;
    if (np == 0){
      v = b2f(base[d]);
    } else {
      int y = (np-1)>>5, x = (np-1)&31;
      #pragma unroll
      for (int ky=0; ky<3; ky++){
        int yy = y+ky-1;
        if (yy<0 || yy>31) continue;
        #pragma unroll
        for (int kx=0; kx<3; kx++){
          int xx = x+kx-1;
          if (xx<0 || xx>31) continue;
          v += w9[d*9+ky*3+kx] * b2f(base[(size_t)(1+yy*32+xx)*kD + d]);
        }
      }
    }
    float s = v, s2 = v*v;
    #pragma unroll
    for (int off=1; off<64; off<<=1){ s += __shfl_xor(s, off); s2 += __shfl_xor(s2, off); }
    float mean = s*(1.f/64.f);
    float var  = s2*(1.f/64.f) - mean*mean;
    v = (v-mean)*rsqrtf(var+1e-5f)*gg[d] + bb2[d];
  }
  if (transposed) out[((size_t)bh*kD + d)*kNP + np] = f2b(v);
  else            out[((size_t)bh*kNP + np)*kD + d] = f2b(v);
}

// ---------------- attention (2-pass, writes attn + ctx) ----------------
__global__ __launch_bounds__(256) void k_attn(const u16* __restrict__ Qp, const u16* __restrict__ Kp,
    const u16* __restrict__ Vt, const int* __restrict__ maskn,
    float* __restrict__ attn_out, u16* __restrict__ ctx){
  __shared__ u16 Pl[4][16][40];
  const int wave = threadIdx.x>>6, lane = threadIdx.x&63;
  const int gw = blockIdx.x*4 + wave;     // 0..6239
  const int qt = gw % 65;
  const int bh = gw / 65;
  const int b  = bh / 12, h = bh - b*12;
  const int qbase = qt*16;
  const int g = lane>>4, cl = lane&15;

  const u16* qrow = Qp + ((size_t)bh*kNP + (qbase + cl))*kD + g*8;
  bf16x8 aq0 = *reinterpret_cast<const bf16x8*>(qrow);
  bf16x8 aq1 = *reinterpret_cast<const bf16x8*>(qrow + 32);

  int qi_[4]; float mq[4];
  #pragma unroll
  for (int i=0;i<4;i++){
    int qi = qbase + g*4 + i; qi_[i]=qi;
    mq[i] = (qi<kN && maskn[b*kN+qi]!=0) ? 1.f : 0.f;
  }

  const u16* kb = Kp + (size_t)bh*kNP*kD;
  float m_r[4], l_r[4];
  #pragma unroll
  for (int i=0;i<4;i++){ m_r[i] = -3.0e38f; l_r[i] = 0.f; }

  // pass 1: row stats
  for (int kt=0; kt<33; kt++){
    const int ktb = kt*32;
    const u16* kr = kb + (size_t)(ktb+cl)*kD + g*8;
    bf16x8 b00 = *reinterpret_cast<const bf16x8*>(kr);
    bf16x8 b01 = *reinterpret_cast<const bf16x8*>(kr+32);
    bf16x8 b10 = *reinterpret_cast<const bf16x8*>(kr+1024);
    bf16x8 b11 = *reinterpret_cast<const bf16x8*>(kr+1024+32);
    f32x4 s0 = {0.f,0.f,0.f,0.f}, s1 = {0.f,0.f,0.f,0.f};
    s0 = MFMA16(aq0,b00,s0); s0 = MFMA16(aq1,b01,s0);
    s1 = MFMA16(aq0,b10,s1); s1 = MFMA16(aq1,b11,s1);
    const bool v0 = (ktb+cl)<kN, v1 = (ktb+16+cl)<kN;
    #pragma unroll
    for (int i=0;i<4;i++){
      float lg0 = v0 ? (mq[i]>0.f ? s0[i]*kScale : -10000.f) : -3.0e38f;
      float lg1 = v1 ? (mq[i]>0.f ? s1[i]*kScale : -10000.f) : -3.0e38f;
      float mx = fmaxf(m_r[i], fmaxf(lg0,lg1));
      if (mx > -1.0e38f){
        float a = (m_r[i] > -1.0e38f) ? l_r[i]*__expf(m_r[i]-mx) : 0.f;
        a += (lg0 > -1.0e38f) ? __expf(lg0-mx) : 0.f;
        a += (lg1 > -1.0e38f) ? __expf(lg1-mx) : 0.f;
        l_r[i] = a; m_r[i] = mx;
      }
    }
  }
  // reduce (m,l) across the 16 lanes that hold each row
  #pragma unroll
  for (int off=1; off<16; off<<=1){
    #pragma unroll
    for (int i=0;i<4;i++){
      float mo = __shfl_xor(m_r[i], off);
      float lo = __shfl_xor(l_r[i], off);
      float mx = fmaxf(m_r[i], mo);
      float a = (m_r[i] > -1.0e38f ? l_r[i]*__expf(m_r[i]-mx) : 0.f)
              + (mo     > -1.0e38f ? lo   *__expf(mo    -mx) : 0.f);
      m_r[i] = mx; l_r[i] = a;
    }
  }
  float inv_l[4];
  #pragma unroll
  for (int i=0;i<4;i++) inv_l[i] = 1.f/l_r[i];

  // pass 2: recompute, write attn, accumulate PV
  f32x4 o[4];
  #pragma unroll
  for (int fn=0;fn<4;fn++) o[fn] = (f32x4){0.f,0.f,0.f,0.f};

  float* aout = attn_out + (size_t)bh*kN*kN;
  const u16* vb_base = Vt + (size_t)bh*kD*kNP;

  for (int kt=0; kt<33; kt++){
    const int ktb = kt*32;
    const u16* kr = kb + (size_t)(ktb+cl)*kD + g*8;
    bf16x8 b00 = *reinterpret_cast<const bf16x8*>(kr);
    bf16x8 b01 = *reinterpret_cast<const bf16x8*>(kr+32);
    bf16x8 b10 = *reinterpret_cast<const bf16x8*>(kr+1024);
    bf16x8 b11 = *reinterpret_cast<const bf16x8*>(kr+1024+32);
    f32x4 s0 = {0.f,0.f,0.f,0.f}, s1 = {0.f,0.f,0.f,0.f};
    s0 = MFMA16(aq0,b00,s0); s0 = MFMA16(aq1,b01,s0);
    s1 = MFMA16(aq0,b10,s1); s1 = MFMA16(aq1,b11,s1);
    const int k0c = ktb+cl, k1c = ktb+16+cl;
    #pragma unroll
    for (int i=0;i<4;i++){
      float p0 = 0.f, p1 = 0.f;
      if (k0c < kN){
        float lg = mq[i]>0.f ? s0[i]*kScale : -10000.f;
        p0 = __expf(lg - m_r[i]) * inv_l[i];
        if (qi_[i] < kN) aout[(size_t)qi_[i]*kN + k0c] = p0;
      }
      if (k1c < kN){
        float lg = mq[i]>0.f ? s1[i]*kScale : -10000.f;
        p1 = __expf(lg - m_r[i]) * inv_l[i];
        if (qi_[i] < kN) aout[(size_t)qi_[i]*kN + k1c] = p1;
      }
      Pl[wave][g*4+i][cl]    = f2b(p0);
      Pl[wave][g*4+i][16+cl] = f2b(p1);
    }
    bf16x8 pa = *reinterpret_cast<const bf16x8*>(&Pl[wave][cl][g*8]);
    #pragma unroll
    for (int fn=0; fn<4; fn++){
      bf16x8 vb = *reinterpret_cast<const bf16x8*>(vb_base + (size_t)(fn*16+cl)*kNP + ktb + g*8);
      o[fn] = MFMA16(pa, vb, o[fn]);
    }
  }
  // epilogue: residual (+q for spatial tokens) -> ctx bf16 (B,N,C)
  #pragma unroll
  for (int fn=0; fn<4; fn++){
    #pragma unroll
    for (int i=0;i<4;i++){
      int qi = qi_[i];
      if (qi >= kN) continue;
      int dd = fn*16 + cl;
      float val = o[fn][i];
      if (qi >= 1) val += b2f(Qp[((size_t)bh*kNP + qi)*kD + dd]);
      ctx[((size_t)(b*kN + qi))*kC + h*kD + dd] = f2b(val);
    }
  }
}

// ---------------- output projection ----------------
__global__ __launch_bounds__(256) void k_gemm_proj(const u16* __restrict__ ctx,
                                                   const u16* __restrict__ wpb,
                                                   const float* __restrict__ bp,
                                                   float* __restrict__ out){
  __shared__ u16 As[64][40];
  __shared__ u16 Bs[64][40];
  const int m0 = blockIdx.x*64;
  const int J0 = blockIdx.y*64;
  const int t = threadIdx.x;
  const int lr = t>>2, lc=(t&3)*8;
  const int wave=t>>6, lane=t&63;
  const int wr=(wave>>1)*32, wc=(wave&1)*32;
  const int g=lane>>4, cl=lane&15;
  f32x4 acc[2][2];
  #pragma unroll
  for (int fm=0;fm<2;fm++)
    #pragma unroll
    for (int fn=0;fn<2;fn++) acc[fm][fn] = (f32x4){0.f,0.f,0.f,0.f};

  for (int k0=0; k0<768; k0+=32){
    __syncthreads();
    uint4 av = {0u,0u,0u,0u};
    int gm = m0 + lr;
    if (gm < kM) av = *reinterpret_cast<const uint4*>(ctx + (size_t)gm*768 + k0 + lc);
    *reinterpret_cast<uint4*>(&As[lr][lc]) = av;
    uint4 bv = *reinterpret_cast<const uint4*>(wpb + (size_t)(J0+lr)*768 + k0 + lc);
    *reinterpret_cast<uint4*>(&Bs[lr][lc]) = bv;
    __syncthreads();
    bf16x8 a0 = *reinterpret_cast<const bf16x8*>(&As[wr+cl][g*8]);
    bf16x8 a1 = *reinterpret_cast<const bf16x8*>(&As[wr+16+cl][g*8]);
    bf16x8 b0 = *reinterpret_cast<const bf16x8*>(&Bs[wc+cl][g*8]);
    bf16x8 b1 = *reinterpret_cast<const bf16x8*>(&Bs[wc+16+cl][g*8]);
    acc[0][0] = MFMA16(a0,b0,acc[0][0]);
    acc[0][1] = MFMA16(a0,b1,acc[0][1]);
    acc[1][0] = MFMA16(a1,b0,acc[1][0]);
    acc[1][1] = MFMA16(a1,b1,acc[1][1]);
  }
  #pragma unroll
  for (int fm=0;fm<2;fm++){
    #pragma unroll
    for (int fn=0;fn<2;fn++){
      #pragma unroll
      for (int i=0;i<4;i++){
        int gm = m0 + wr + fm*16 + g*4 + i;
        if (gm >= kM) continue;
        int gc = J0 + wc + fn*16 + cl;
        out[(size_t)gm*768 + gc] = acc[fm][fn][i] + bp[gc];
      }
    }
  }
}

extern "C" void kernel_launch(void* const* d_in, const int* in_sizes, int n_in,
                              void* d_out, int out_size, void* d_ws, size_t ws_size,
                              hipStream_t stream) {
  const float* x    = (const float*)d_in[0];
  const void*  msk  = d_in[1];
  const float* Wq   = (const float*)d_in[2];
  const float* Wk   = (const float*)d_in[3];
  const float* Wv   = (const float*)d_in[4];
  const float* pw_q = (const float*)d_in[5];
  const float* pw_k = (const float*)d_in[6];
  const float* pw_v = (const float*)d_in[7];
  const float* gq   = (const float*)d_in[8];
  const float* bq   = (const float*)d_in[9];
  const float* gk   = (const float*)d_in[10];
  const float* bk   = (const float*)d_in[11];
  const float* gv   = (const float*)d_in[12];
  const float* bv   = (const float*)d_in[13];
  const float* Wp   = (const float*)d_in[14];
  const float* bp   = (const float*)d_in[15];

  char* ws = (char*)d_ws;
  u16* xb    = (u16*)(ws + 0);            // x bf16: 12,595,200 B
  u16* wb    = (u16*)(ws + 12595200);     // Wq,Wk,Wv,Wp bf16: 4,718,592 B
  int* maskn = (int*)(ws + 17313792);     // 8200 int32
  u16* qkv   = (u16*)(ws + 17346816);     // unpooled q,k,v bf16: 3*12,595,200 B
  u16* Qp    = (u16*)(ws + 55132416);     // pooled q bf16 [bh][1056][64]
  u16* Kp    = (u16*)(ws + 68108544);     // pooled k bf16 [bh][1056][64]
  u16* Vt    = (u16*)(ws + 81084672);     // pooled v bf16 transposed [bh][64][1056]
  u16* ctx   = (u16*)(ws + 17346816);     // aliases qkv (free after pooling)

  float* out1 = (float*)d_out;
  float* attn = out1 + (size_t)kM*kC;     // 6,297,600 floats in, then 100,860,000

  k_conv_x<<<2048, 256, 0, stream>>>(reinterpret_cast<const float4*>(x), xb, (kM*kC)/4);
  k_conv_w<<<dim3(576,4), 256, 0, stream>>>(Wq, Wk, Wv, Wp, wb);
  k_mask<<<1, 256, 0, stream>>>((const unsigned char*)msk, maskn, kM);
  k_gemm_qkv<<<dim3(129,36), 256, 0, stream>>>(xb, wb, qkv);
  k_pool<<<kBH*264, 256, 0, stream>>>(qkv,            pw_q, gq, bq, Qp, 0);
  k_pool<<<kBH*264, 256, 0, stream>>>(qkv +  6297600, pw_k, gk, bk, Kp, 0);
  k_pool<<<kBH*264, 256, 0, stream>>>(qkv + 12595200, pw_v, gv, bv, Vt, 1);
  k_attn<<<1560, 256, 0, stream>>>(Qp, Kp, Vt, maskn, attn, ctx);
  k_gemm_proj<<<dim3(129,12), 256, 0, stream>>>(ctx, wb + (size_t)3*589824, bp, out1);
}

// Round 2
// 514.695 us; speedup vs baseline: 1.3147x; 1.3147x over previous
//
#include <hip/hip_runtime.h>
#include <hip/hip_bf16.h>
#include <cstdint>
#include <cstddef>

typedef unsigned short u16;
typedef __attribute__((ext_vector_type(8))) short bf16x8;
typedef __attribute__((ext_vector_type(4))) float f32x4;

#define MFMA16(a,b,c) __builtin_amdgcn_mfma_f32_16x16x32_bf16(a,b,c,0,0,0)

static constexpr int kB = 8, kH = 12, kN = 1025, kC = 768, kD = 64;
static constexpr int kBH = kB*kH;          // 96
static constexpr int kNP = 1056;           // padded N (33*32)
static constexpr int kM  = kB*kN;          // 8200
static constexpr float kScale = 0.125f;

__device__ __forceinline__ u16 f2b(float f){
  unsigned u = __builtin_bit_cast(unsigned, f);
  u = (u + 0x7fffu + ((u>>16)&1u)) >> 16;
  return (u16)u;
}
__device__ __forceinline__ float b2f(u16 s){
  unsigned u = ((unsigned)s)<<16;
  return __builtin_bit_cast(float, u);
}

// ---------------- conversions ----------------
__global__ void k_conv_x(const float4* __restrict__ x, u16* __restrict__ out, int n4){
  int i = blockIdx.x*blockDim.x + threadIdx.x;
  int stride = gridDim.x*blockDim.x;
  for (; i<n4; i+=stride){
    float4 v = x[i];
    ushort4 o;
    o.x=f2b(v.x); o.y=f2b(v.y); o.z=f2b(v.z); o.w=f2b(v.w);
    *reinterpret_cast<ushort4*>(out + (size_t)i*4) = o;
  }
}

__global__ void k_conv_w(const float* __restrict__ w0, const float* __restrict__ w1,
                         const float* __restrict__ w2, const float* __restrict__ w3,
                         u16* __restrict__ out){
  const float* ws[4] = {w0,w1,w2,w3};
  int sel = blockIdx.y;
  const float4* src = reinterpret_cast<const float4*>(ws[sel]);
  int i = blockIdx.x*blockDim.x + threadIdx.x;   // 0..147455
  float4 v = src[i];
  ushort4 o;
  o.x=f2b(v.x); o.y=f2b(v.y); o.z=f2b(v.z); o.w=f2b(v.w);
  *reinterpret_cast<ushort4*>(out + (size_t)sel*589824 + (size_t)i*4) = o;
}

// mask may arrive as bool8 / int32 / float32 — detect via nonzero-byte density.
__global__ void k_mask(const unsigned char* __restrict__ m, int* __restrict__ out, int n){
  __shared__ int cnt;
  if (threadIdx.x==0) cnt = 0;
  __syncthreads();
  int local = 0;
  for (int i=threadIdx.x; i<1024; i+=blockDim.x) local += (m[i]!=0);
  atomicAdd(&cnt, local);
  __syncthreads();
  bool b8 = (cnt > 512);   // bool8 w/ ~90% ones -> ~922; int32 -> ~230; f32 -> ~461
  for (int i=threadIdx.x; i<n; i+=blockDim.x){
    int v = b8 ? (m[i]!=0) : (reinterpret_cast<const int*>(m)[i] != 0);
    out[i] = v;
  }
}

// ---------------- QKV GEMM ----------------
__global__ __launch_bounds__(256) void k_gemm_qkv(const u16* __restrict__ xb,
                                                  const u16* __restrict__ wb,
                                                  u16* __restrict__ qkv){
  __shared__ u16 As[64][40];
  __shared__ u16 Bs[64][40];
  const int m0 = blockIdx.x*64;
  const int J0 = blockIdx.y*64;
  const int sel = J0/768;
  const int jb  = J0%768;
  const u16* W = wb + (size_t)sel*589824;
  const int t = threadIdx.x;
  const int lr = t>>2, lc=(t&3)*8;
  const int wave=t>>6, lane=t&63;
  const int wr=(wave>>1)*32, wc=(wave&1)*32;
  const int g=lane>>4, cl=lane&15;
  f32x4 acc[2][2];
  #pragma unroll
  for (int fm=0;fm<2;fm++)
    #pragma unroll
    for (int fn=0;fn<2;fn++) acc[fm][fn] = (f32x4){0.f,0.f,0.f,0.f};

  for (int k0=0; k0<768; k0+=32){
    __syncthreads();
    uint4 av = {0u,0u,0u,0u};
    int gm = m0 + lr;
    if (gm < kM) av = *reinterpret_cast<const uint4*>(xb + (size_t)gm*768 + k0 + lc);
    *reinterpret_cast<uint4*>(&As[lr][lc]) = av;
    uint4 bv = *reinterpret_cast<const uint4*>(W + (size_t)(jb+lr)*768 + k0 + lc);
    *reinterpret_cast<uint4*>(&Bs[lr][lc]) = bv;
    __syncthreads();
    bf16x8 a0 = *reinterpret_cast<const bf16x8*>(&As[wr+cl][g*8]);
    bf16x8 a1 = *reinterpret_cast<const bf16x8*>(&As[wr+16+cl][g*8]);
    bf16x8 b0 = *reinterpret_cast<const bf16x8*>(&Bs[wc+cl][g*8]);
    bf16x8 b1 = *reinterpret_cast<const bf16x8*>(&Bs[wc+16+cl][g*8]);
    acc[0][0] = MFMA16(a0,b0,acc[0][0]);
    acc[0][1] = MFMA16(a0,b1,acc[0][1]);
    acc[1][0] = MFMA16(a1,b0,acc[1][0]);
    acc[1][1] = MFMA16(a1,b1,acc[1][1]);
  }
  #pragma unroll
  for (int fm=0;fm<2;fm++){
    #pragma unroll
    for (int fn=0;fn<2;fn++){
      #pragma unroll
      for (int i=0;i<4;i++){
        int gm = m0 + wr + fm*16 + g*4 + i;
        if (gm >= kM) continue;
        int gc = jb + wc + fn*16 + cl;       // col within 768
        int b = gm/1025, n = gm - b*1025;
        int h = gc>>6, dd = gc&63;
        qkv[(size_t)sel*6297600 + (((size_t)(b*12+h))*1025 + n)*64 + dd] = f2b(acc[fm][fn][i]);
      }
    }
  }
}

// ---------------- depthwise pool + layernorm ----------------
__global__ __launch_bounds__(256) void k_pool(const u16* __restrict__ in, const float* __restrict__ w9,
    const float* __restrict__ gg, const float* __restrict__ bb2, u16* __restrict__ out, int transposed){
  const int wave = threadIdx.x>>6, d = threadIdx.x&63;
  const int grp = blockIdx.x % 264;
  const int bh  = blockIdx.x / 264;
  const int np  = grp*4 + wave;
  float v = 0.f;
  if (np < kN){
    const u16* base = in + (size_t)bh*kN*kD;
    if (np == 0){
      v = b2f(base[d]);
    } else {
      int y = (np-1)>>5, x = (np-1)&31;
      #pragma unroll
      for (int ky=0; ky<3; ky++){
        int yy = y+ky-1;
        if (yy<0 || yy>31) continue;
        #pragma unroll
        for (int kx=0; kx<3; kx++){
          int xx = x+kx-1;
          if (xx<0 || xx>31) continue;
          v += w9[d*9+ky*3+kx] * b2f(base[(size_t)(1+yy*32+xx)*kD + d]);
        }
      }
    }
    float s = v, s2 = v*v;
    #pragma unroll
    for (int off=1; off<64; off<<=1){ s += __shfl_xor(s, off); s2 += __shfl_xor(s2, off); }
    float mean = s*(1.f/64.f);
    float var  = s2*(1.f/64.f) - mean*mean;
    v = (v-mean)*rsqrtf(var+1e-5f)*gg[d] + bb2[d];
  }
  if (transposed) out[((size_t)bh*kD + d)*kNP + np] = f2b(v);
  else            out[((size_t)bh*kNP + np)*kD + d] = f2b(v);
}

// ---------------- attention: single QK^T pass + LDS e-tile ----------------
// block = 4 waves, one (bh, 16-row q-tile). No max subtraction needed:
// LN'd q,k => |logit| <= ||q||*||k||*scale = 8*8*0.125 = 8, exp never overflows.
// masked rows: logit := 0 uniformly -> softmax = 1/1025 exactly (matches ref).
__global__ __launch_bounds__(256) void k_attn(const u16* __restrict__ Qp, const u16* __restrict__ Kp,
    const u16* __restrict__ Vt, const int* __restrict__ maskn,
    float* __restrict__ attn_out, u16* __restrict__ ctx){
  constexpr int LDE = 1064;                 // padded row stride (elems): 2128 B
  __shared__ u16 E[16*LDE];                 // 34048 B e-tile (bf16)
  __shared__ float Lrow[16];
  const int wave = threadIdx.x>>6, lane = threadIdx.x&63;
  const int bh = blockIdx.x / 65;
  const int qt = blockIdx.x % 65;
  const int b  = bh / 12, h = bh - b*12;
  const int qbase = qt*16;
  const int g = lane>>4, cl = lane&15;

  if (threadIdx.x < 16) Lrow[threadIdx.x] = 0.f;
  __syncthreads();

  // Q fragments for rows qbase..qbase+15 (A-layout: lane row = cl, k = g*8..)
  const u16* qrow = Qp + ((size_t)bh*kNP + (qbase + cl))*kD + g*8;
  bf16x8 aq0 = *reinterpret_cast<const bf16x8*>(qrow);
  bf16x8 aq1 = *reinterpret_cast<const bf16x8*>(qrow + 32);

  float mq[4];                              // row-mask * scale (0 if masked)
  #pragma unroll
  for (int i=0;i<4;i++){
    int qi = qbase + g*4 + i;
    mq[i] = (qi<kN && maskn[b*kN+qi]!=0) ? kScale : 0.f;
  }

  // ---- phase 1: QK^T -> e = exp(lg) -> LDS, accumulate row sums ----
  const u16* kb = Kp + (size_t)bh*kNP*kD;
  float rsum[4] = {0.f,0.f,0.f,0.f};
  for (int kt=wave; kt<33; kt+=4){
    const int ktb = kt*32;
    const u16* kr = kb + (size_t)(ktb+cl)*kD + g*8;
    bf16x8 b00 = *reinterpret_cast<const bf16x8*>(kr);
    bf16x8 b01 = *reinterpret_cast<const bf16x8*>(kr+32);
    bf16x8 b10 = *reinterpret_cast<const bf16x8*>(kr+1024);
    bf16x8 b11 = *reinterpret_cast<const bf16x8*>(kr+1024+32);
    f32x4 s0 = {0.f,0.f,0.f,0.f}, s1 = {0.f,0.f,0.f,0.f};
    s0 = MFMA16(aq0,b00,s0); s0 = MFMA16(aq1,b01,s0);
    s1 = MFMA16(aq0,b10,s1); s1 = MFMA16(aq1,b11,s1);
    const bool v0 = (ktb+cl)<kN, v1 = (ktb+16+cl)<kN;
    #pragma unroll
    for (int i=0;i<4;i++){
      int row = g*4+i;
      float e0 = v0 ? __expf(s0[i]*mq[i]) : 0.f;
      float e1 = v1 ? __expf(s1[i]*mq[i]) : 0.f;
      rsum[i] += e0 + e1;
      E[row*LDE + ktb + cl]      = f2b(e0);
      E[row*LDE + ktb + 16 + cl] = f2b(e1);
    }
  }
  // reduce row sums across the 16 'cl' lanes, then one atomic per (g,i)
  #pragma unroll
  for (int off=1; off<16; off<<=1){
    #pragma unroll
    for (int i=0;i<4;i++) rsum[i] += __shfl_xor(rsum[i], off);
  }
  if (cl == 0){
    #pragma unroll
    for (int i=0;i<4;i++) atomicAdd(&Lrow[g*4+i], rsum[i]);
  }
  __syncthreads();

  // ---- phase 2b: PV from LDS e-tile; wave owns 16 d-cols ----
  const int d0 = wave*16;
  f32x4 oacc = (f32x4){0.f,0.f,0.f,0.f};
  const u16* vb = Vt + ((size_t)bh*kD + d0 + cl)*kNP;
  for (int kt=0; kt<33; kt++){
    const int ko = kt*32 + g*8;
    bf16x8 pa  = *reinterpret_cast<const bf16x8*>(&E[cl*LDE + ko]);
    bf16x8 vbf = *reinterpret_cast<const bf16x8*>(vb + ko);
    oacc = MFMA16(pa, vbf, oacc);
  }
  #pragma unroll
  for (int i=0;i<4;i++){
    int row = g*4+i, qi = qbase+row;
    if (qi < kN){
      float val = oacc[i] * (1.f/Lrow[row]);
      int dd = d0 + cl;
      if (qi >= 1) val += b2f(Qp[((size_t)bh*kNP + qi)*kD + dd]);
      ctx[((size_t)(b*kN + qi))*kC + h*kD + dd] = f2b(val);
    }
  }

  // ---- phase 2a: normalized attn store (coalesced 256B dword stores) ----
  float* abase = attn_out + (size_t)bh*kN*kN;
  #pragma unroll
  for (int r=wave*4; r<wave*4+4; ++r){
    int qi = qbase + r;
    if (qi >= kN) continue;
    float inv = 1.f/Lrow[r];
    float* arow = abase + (size_t)qi*kN;
    const u16* erow = &E[r*LDE];
    for (int c = lane; c < kN; c += 64){
      arow[c] = b2f(erow[c]) * inv;
    }
  }
}

// ---------------- output projection ----------------
__global__ __launch_bounds__(256) void k_gemm_proj(const u16* __restrict__ ctx,
                                                   const u16* __restrict__ wpb,
                                                   const float* __restrict__ bp,
                                                   float* __restrict__ out){
  __shared__ u16 As[64][40];
  __shared__ u16 Bs[64][40];
  const int m0 = blockIdx.x*64;
  const int J0 = blockIdx.y*64;
  const int t = threadIdx.x;
  const int lr = t>>2, lc=(t&3)*8;
  const int wave=t>>6, lane=t&63;
  const int wr=(wave>>1)*32, wc=(wave&1)*32;
  const int g=lane>>4, cl=lane&15;
  f32x4 acc[2][2];
  #pragma unroll
  for (int fm=0;fm<2;fm++)
    #pragma unroll
    for (int fn=0;fn<2;fn++) acc[fm][fn] = (f32x4){0.f,0.f,0.f,0.f};

  for (int k0=0; k0<768; k0+=32){
    __syncthreads();
    uint4 av = {0u,0u,0u,0u};
    int gm = m0 + lr;
    if (gm < kM) av = *reinterpret_cast<const uint4*>(ctx + (size_t)gm*768 + k0 + lc);
    *reinterpret_cast<uint4*>(&As[lr][lc]) = av;
    uint4 bv = *reinterpret_cast<const uint4*>(wpb + (size_t)(J0+lr)*768 + k0 + lc);
    *reinterpret_cast<uint4*>(&Bs[lr][lc]) = bv;
    __syncthreads();
    bf16x8 a0 = *reinterpret_cast<const bf16x8*>(&As[wr+cl][g*8]);
    bf16x8 a1 = *reinterpret_cast<const bf16x8*>(&As[wr+16+cl][g*8]);
    bf16x8 b0 = *reinterpret_cast<const bf16x8*>(&Bs[wc+cl][g*8]);
    bf16x8 b1 = *reinterpret_cast<const bf16x8*>(&Bs[wc+16+cl][g*8]);
    acc[0][0] = MFMA16(a0,b0,acc[0][0]);
    acc[0][1] = MFMA16(a0,b1,acc[0][1]);
    acc[1][0] = MFMA16(a1,b0,acc[1][0]);
    acc[1][1] = MFMA16(a1,b1,acc[1][1]);
  }
  #pragma unroll
  for (int fm=0;fm<2;fm++){
    #pragma unroll
    for (int fn=0;fn<2;fn++){
      #pragma unroll
      for (int i=0;i<4;i++){
        int gm = m0 + wr + fm*16 + g*4 + i;
        if (gm >= kM) continue;
        int gc = J0 + wc + fn*16 + cl;
        out[(size_t)gm*768 + gc] = acc[fm][fn][i] + bp[gc];
      }
    }
  }
}

extern "C" void kernel_launch(void* const* d_in, const int* in_sizes, int n_in,
                              void* d_out, int out_size, void* d_ws, size_t ws_size,
                              hipStream_t stream) {
  const float* x    = (const float*)d_in[0];
  const void*  msk  = d_in[1];
  const float* Wq   = (const float*)d_in[2];
  const float* Wk   = (const float*)d_in[3];
  const float* Wv   = (const float*)d_in[4];
  const float* pw_q = (const float*)d_in[5];
  const float* pw_k = (const float*)d_in[6];
  const float* pw_v = (const float*)d_in[7];
  const float* gq   = (const float*)d_in[8];
  const float* bq   = (const float*)d_in[9];
  const float* gk   = (const float*)d_in[10];
  const float* bk   = (const float*)d_in[11];
  const float* gv   = (const float*)d_in[12];
  const float* bv   = (const float*)d_in[13];
  const float* Wp   = (const float*)d_in[14];
  const float* bp   = (const float*)d_in[15];

  char* ws = (char*)d_ws;
  u16* xb    = (u16*)(ws + 0);            // x bf16: 12,595,200 B
  u16* wb    = (u16*)(ws + 12595200);     // Wq,Wk,Wv,Wp bf16: 4,718,592 B
  int* maskn = (int*)(ws + 17313792);     // 8200 int32
  u16* qkv   = (u16*)(ws + 17346816);     // unpooled q,k,v bf16: 3*12,595,200 B
  u16* Qp    = (u16*)(ws + 55132416);     // pooled q bf16 [bh][1056][64]
  u16* Kp    = (u16*)(ws + 68108544);     // pooled k bf16 [bh][1056][64]
  u16* Vt    = (u16*)(ws + 81084672);     // pooled v bf16 transposed [bh][64][1056]
  u16* ctx   = (u16*)(ws + 17346816);     // aliases qkv (free after pooling)

  float* out1 = (float*)d_out;
  float* attn = out1 + (size_t)kM*kC;     // 6,297,600 floats, then 100,860,000

  k_conv_x<<<2048, 256, 0, stream>>>(reinterpret_cast<const float4*>(x), xb, (kM*kC)/4);
  k_conv_w<<<dim3(576,4), 256, 0, stream>>>(Wq, Wk, Wv, Wp, wb);
  k_mask<<<1, 256, 0, stream>>>((const unsigned char*)msk, maskn, kM);
  k_gemm_qkv<<<dim3(129,36), 256, 0, stream>>>(xb, wb, qkv);
  k_pool<<<kBH*264, 256, 0, stream>>>(qkv,            pw_q, gq, bq, Qp, 0);
  k_pool<<<kBH*264, 256, 0, stream>>>(qkv +  6297600, pw_k, gk, bk, Kp, 0);
  k_pool<<<kBH*264, 256, 0, stream>>>(qkv + 12595200, pw_v, gv, bv, Vt, 1);
  k_attn<<<96*65, 256, 0, stream>>>(Qp, Kp, Vt, maskn, attn, ctx);
  k_gemm_proj<<<dim3(129,12), 256, 0, stream>>>(ctx, wb + (size_t)3*589824, bp, out1);
}

// Round 3
// 475.957 us; speedup vs baseline: 1.4217x; 1.0814x over previous
//
#include <hip/hip_runtime.h>
#include <hip/hip_bf16.h>
#include <cstdint>
#include <cstddef>

typedef unsigned short u16;
typedef __attribute__((ext_vector_type(8))) short bf16x8;
typedef __attribute__((ext_vector_type(4))) float f32x4;

#define MFMA16(a,b,c) __builtin_amdgcn_mfma_f32_16x16x32_bf16(a,b,c,0,0,0)
#define GLL16(gp, lp) __builtin_amdgcn_global_load_lds( \
    (const __attribute__((address_space(1))) void*)(gp), \
    (__attribute__((address_space(3))) void*)(lp), 16, 0, 0)

static constexpr int kB = 8, kH = 12, kN = 1025, kC = 768, kD = 64;
static constexpr int kBH = kB*kH;          // 96
static constexpr int kNP = 1056;           // padded N (33*32)
static constexpr int kM  = kB*kN;          // 8200
static constexpr float kScale = 0.125f;

__device__ __forceinline__ u16 f2b(float f){
  unsigned u = __builtin_bit_cast(unsigned, f);
  u = (u + 0x7fffu + ((u>>16)&1u)) >> 16;
  return (u16)u;
}
__device__ __forceinline__ float b2f(u16 s){
  unsigned u = ((unsigned)s)<<16;
  return __builtin_bit_cast(float, u);
}

// ---------------- conversions ----------------
__global__ void k_conv_x(const float4* __restrict__ x, u16* __restrict__ out, int n4){
  int i = blockIdx.x*blockDim.x + threadIdx.x;
  int stride = gridDim.x*blockDim.x;
  for (; i<n4; i+=stride){
    float4 v = x[i];
    ushort4 o;
    o.x=f2b(v.x); o.y=f2b(v.y); o.z=f2b(v.z); o.w=f2b(v.w);
    *reinterpret_cast<ushort4*>(out + (size_t)i*4) = o;
  }
}

__global__ void k_conv_w(const float* __restrict__ w0, const float* __restrict__ w1,
                         const float* __restrict__ w2, const float* __restrict__ w3,
                         u16* __restrict__ out){
  const float* ws[4] = {w0,w1,w2,w3};
  int sel = blockIdx.y;
  const float4* src = reinterpret_cast<const float4*>(ws[sel]);
  int i = blockIdx.x*blockDim.x + threadIdx.x;   // 0..147455
  float4 v = src[i];
  ushort4 o;
  o.x=f2b(v.x); o.y=f2b(v.y); o.z=f2b(v.z); o.w=f2b(v.w);
  *reinterpret_cast<ushort4*>(out + (size_t)sel*589824 + (size_t)i*4) = o;
}

// mask may arrive as bool8 / int32 / float32 — detect via nonzero-byte density.
__global__ void k_mask(const unsigned char* __restrict__ m, int* __restrict__ out, int n){
  __shared__ int cnt;
  if (threadIdx.x==0) cnt = 0;
  __syncthreads();
  int local = 0;
  for (int i=threadIdx.x; i<1024; i+=blockDim.x) local += (m[i]!=0);
  atomicAdd(&cnt, local);
  __syncthreads();
  bool b8 = (cnt > 512);
  for (int i=threadIdx.x; i<n; i+=blockDim.x){
    int v = b8 ? (m[i]!=0) : (reinterpret_cast<const int*>(m)[i] != 0);
    out[i] = v;
  }
}

// ---------------- 128x128 GEMM (m97 structure: global_load_lds, 2-barrier) ----
// C[m][j] = sum_k A[m][k]*Bm[j][k], A:[Mrows][768], Bm:[*][768], bf16 in.
// MODE 0: qkv epilogue (scatter bf16 per-head); MODE 1: proj epilogue (f32+bias)
template<int MODE>
__global__ __launch_bounds__(256) void k_gemm128(const u16* __restrict__ A,
      const u16* __restrict__ wb, const float* __restrict__ bias,
      u16* __restrict__ outb, float* __restrict__ outf){
  __shared__ u16 sA[128*32];
  __shared__ u16 sB[128*32];
  const int m0 = blockIdx.x*128;
  const int N0 = blockIdx.y*128;
  const int sel = (MODE==0) ? (N0/768) : 3;
  const int jb  = (MODE==0) ? (N0%768) : N0;
  const u16* W = wb + (size_t)sel*589824;
  const int t = threadIdx.x;
  const int wave = t>>6, lane = t&63;
  const int g = lane>>4, cl = lane&15;
  const int wr2 = (wave>>1)*64, wc2 = (wave&1)*64;

  // staging chunk ids (16B each): round r base = r*256 + wave*64 (+lane by HW)
  const int cid0 = wave*64 + lane;
  const int cid1 = cid0 + 256;
  const int ar0 = m0 + (cid0>>2) < kM ? m0 + (cid0>>2) : kM-1;
  const int ar1 = m0 + (cid1>>2) < kM ? m0 + (cid1>>2) : kM-1;
  const int ac0 = (cid0&3)<<3, ac1 = (cid1&3)<<3;
  const int br0 = jb + (cid0>>2), br1 = jb + (cid1>>2);
  u16* lA0 = &sA[(size_t)(wave*64)*8];
  u16* lA1 = &sA[(size_t)(256 + wave*64)*8];
  u16* lB0 = &sB[(size_t)(wave*64)*8];
  u16* lB1 = &sB[(size_t)(256 + wave*64)*8];

  f32x4 acc[4][4];
  #pragma unroll
  for (int i=0;i<4;i++)
    #pragma unroll
    for (int j=0;j<4;j++) acc[i][j] = (f32x4){0.f,0.f,0.f,0.f};

  for (int k0=0; k0<768; k0+=32){
    __syncthreads();   // previous iter's ds_reads done
    GLL16(A + (size_t)ar0*768 + k0 + ac0, lA0);
    GLL16(A + (size_t)ar1*768 + k0 + ac1, lA1);
    GLL16(W + (size_t)br0*768 + k0 + ac0, lB0);
    GLL16(W + (size_t)br1*768 + k0 + ac1, lB1);
    __syncthreads();   // compiler inserts vmcnt(0) drain before barrier
    bf16x8 af[4], bfg[4];
    #pragma unroll
    for (int fm=0; fm<4; fm++)
      af[fm] = *reinterpret_cast<const bf16x8*>(&sA[(wr2+fm*16+cl)*32 + g*8]);
    #pragma unroll
    for (int fn=0; fn<4; fn++)
      bfg[fn] = *reinterpret_cast<const bf16x8*>(&sB[(wc2+fn*16+cl)*32 + g*8]);
    #pragma unroll
    for (int fm=0; fm<4; fm++)
      #pragma unroll
      for (int fn=0; fn<4; fn++)
        acc[fm][fn] = MFMA16(af[fm], bfg[fn], acc[fm][fn]);
  }

  #pragma unroll
  for (int fm=0; fm<4; fm++){
    #pragma unroll
    for (int fn=0; fn<4; fn++){
      #pragma unroll
      for (int i=0;i<4;i++){
        int gm = m0 + wr2 + fm*16 + g*4 + i;
        if (gm >= kM) continue;
        int gc = jb + wc2 + fn*16 + cl;
        if (MODE==0){
          int b = gm/1025, n = gm - b*1025;
          int h = gc>>6, dd = gc&63;
          outb[(size_t)sel*6297600 + (((size_t)(b*12+h))*1025 + n)*64 + dd] = f2b(acc[fm][fn][i]);
        } else {
          outf[(size_t)gm*768 + gc] = acc[fm][fn][i] + bias[gc];
        }
      }
    }
  }
}

// ---------------- depthwise pool + layernorm (3 tensors in one launch) -------
__global__ __launch_bounds__(256) void k_pool3(const u16* __restrict__ qkv,
    const float* __restrict__ wq, const float* __restrict__ wk, const float* __restrict__ wv,
    const float* __restrict__ gq, const float* __restrict__ bq,
    const float* __restrict__ gk, const float* __restrict__ bk,
    const float* __restrict__ gv, const float* __restrict__ bv,
    u16* __restrict__ Qp, u16* __restrict__ Kp, u16* __restrict__ Vt){
  const int which = blockIdx.y;
  const u16* in = qkv + (size_t)which*6297600;
  const float* w9 = (which==0)?wq:(which==1)?wk:wv;
  const float* gg = (which==0)?gq:(which==1)?gk:gv;
  const float* bb2= (which==0)?bq:(which==1)?bk:bv;
  const int transposed = (which==2);
  u16* out = (which==0)?Qp:(which==1)?Kp:Vt;

  const int wave = threadIdx.x>>6, d = threadIdx.x&63;
  const int grp = blockIdx.x % 264;
  const int bh  = blockIdx.x / 264;
  const int np  = grp*4 + wave;
  float v = 0.f;
  if (np < kN){
    const u16* base = in + (size_t)bh*kN*kD;
    if (np == 0){
      v = b2f(base[d]);
    } else {
      int y = (np-1)>>5, x = (np-1)&31;
      #pragma unroll
      for (int ky=0; ky<3; ky++){
        int yy = y+ky-1;
        if (yy<0 || yy>31) continue;
        #pragma unroll
        for (int kx=0; kx<3; kx++){
          int xx = x+kx-1;
          if (xx<0 || xx>31) continue;
          v += w9[d*9+ky*3+kx] * b2f(base[(size_t)(1+yy*32+xx)*kD + d]);
        }
      }
    }
    float s = v, s2 = v*v;
    #pragma unroll
    for (int off=1; off<64; off<<=1){ s += __shfl_xor(s, off); s2 += __shfl_xor(s2, off); }
    float mean = s*(1.f/64.f);
    float var  = s2*(1.f/64.f) - mean*mean;
    v = (v-mean)*rsqrtf(var+1e-5f)*gg[d] + bb2[d];
  }
  if (transposed) out[((size_t)bh*kD + d)*kNP + np] = f2b(v);
  else            out[((size_t)bh*kNP + np)*kD + d] = f2b(v);
}

// ---------------- attention: single QK^T pass + LDS e-tile ----------------
// |logit| <= 8 (LN'd q,k), so no max subtraction. masked rows -> uniform.
__global__ __launch_bounds__(256) void k_attn(const u16* __restrict__ Qp, const u16* __restrict__ Kp,
    const u16* __restrict__ Vt, const int* __restrict__ maskn,
    float* __restrict__ attn_out, u16* __restrict__ ctx){
  constexpr int LDE = 1064;                 // 2128 B row stride: b128-clean
  __shared__ u16 E[16*LDE];
  __shared__ float Lrow[16];
  const int wave = threadIdx.x>>6, lane = threadIdx.x&63;
  const int bh = blockIdx.x / 65;
  const int qt = blockIdx.x % 65;
  const int b  = bh / 12, h = bh - b*12;
  const int qbase = qt*16;
  const int g = lane>>4, cl = lane&15;

  if (threadIdx.x < 16) Lrow[threadIdx.x] = 0.f;
  __syncthreads();

  const u16* qrow = Qp + ((size_t)bh*kNP + (qbase + cl))*kD + g*8;
  bf16x8 aq0 = *reinterpret_cast<const bf16x8*>(qrow);
  bf16x8 aq1 = *reinterpret_cast<const bf16x8*>(qrow + 32);

  float mq[4];
  #pragma unroll
  for (int i=0;i<4;i++){
    int qi = qbase + g*4 + i;
    mq[i] = (qi<kN && maskn[b*kN+qi]!=0) ? kScale : 0.f;
  }

  // ---- phase 1: QK^T -> e -> LDS, row sums ----
  const u16* kb = Kp + (size_t)bh*kNP*kD;
  float rsum[4] = {0.f,0.f,0.f,0.f};
  for (int kt=wave; kt<33; kt+=4){
    const int ktb = kt*32;
    const u16* kr = kb + (size_t)(ktb+cl)*kD + g*8;
    bf16x8 b00 = *reinterpret_cast<const bf16x8*>(kr);
    bf16x8 b01 = *reinterpret_cast<const bf16x8*>(kr+32);
    bf16x8 b10 = *reinterpret_cast<const bf16x8*>(kr+1024);
    bf16x8 b11 = *reinterpret_cast<const bf16x8*>(kr+1024+32);
    f32x4 s0 = {0.f,0.f,0.f,0.f}, s1 = {0.f,0.f,0.f,0.f};
    s0 = MFMA16(aq0,b00,s0); s0 = MFMA16(aq1,b01,s0);
    s1 = MFMA16(aq0,b10,s1); s1 = MFMA16(aq1,b11,s1);
    const bool v0 = (ktb+cl)<kN, v1 = (ktb+16+cl)<kN;
    #pragma unroll
    for (int i=0;i<4;i++){
      int row = g*4+i;
      float e0 = v0 ? __expf(s0[i]*mq[i]) : 0.f;
      float e1 = v1 ? __expf(s1[i]*mq[i]) : 0.f;
      rsum[i] += e0 + e1;
      E[row*LDE + ktb + cl]      = f2b(e0);
      E[row*LDE + ktb + 16 + cl] = f2b(e1);
    }
  }
  #pragma unroll
  for (int off=1; off<16; off<<=1){
    #pragma unroll
    for (int i=0;i<4;i++) rsum[i] += __shfl_xor(rsum[i], off);
  }
  if (cl == 0){
    #pragma unroll
    for (int i=0;i<4;i++) atomicAdd(&Lrow[g*4+i], rsum[i]);
  }
  __syncthreads();

  // ---- phase 2a FIRST: queue the 410MB of attn stores (fire-and-forget),
  //      they drain under phase 2b's LDS+MFMA work ----
  float* abase = attn_out + (size_t)bh*kN*kN;
  #pragma unroll
  for (int r=wave*4; r<wave*4+4; ++r){
    int qi = qbase + r;
    if (qi >= kN) continue;
    float inv = 1.f/Lrow[r];
    float* arow = abase + (size_t)qi*kN;
    const u16* erow = &E[r*LDE];
    for (int c = lane; c < kN; c += 64){
      arow[c] = b2f(erow[c]) * inv;
    }
  }

  // ---- phase 2b: PV from LDS e-tile; wave owns 16 d-cols ----
  const int d0 = wave*16;
  f32x4 oacc = (f32x4){0.f,0.f,0.f,0.f};
  const u16* vb = Vt + ((size_t)bh*kD + d0 + cl)*kNP;
  for (int kt=0; kt<33; kt++){
    const int ko = kt*32 + g*8;
    bf16x8 pa  = *reinterpret_cast<const bf16x8*>(&E[cl*LDE + ko]);
    bf16x8 vbf = *reinterpret_cast<const bf16x8*>(vb + ko);
    oacc = MFMA16(pa, vbf, oacc);
  }
  #pragma unroll
  for (int i=0;i<4;i++){
    int row = g*4+i, qi = qbase+row;
    if (qi < kN){
      float val = oacc[i] * (1.f/Lrow[row]);
      int dd = d0 + cl;
      if (qi >= 1) val += b2f(Qp[((size_t)bh*kNP + qi)*kD + dd]);
      ctx[((size_t)(b*kN + qi))*kC + h*kD + dd] = f2b(val);
    }
  }
}

extern "C" void kernel_launch(void* const* d_in, const int* in_sizes, int n_in,
                              void* d_out, int out_size, void* d_ws, size_t ws_size,
                              hipStream_t stream) {
  const float* x    = (const float*)d_in[0];
  const void*  msk  = d_in[1];
  const float* Wq   = (const float*)d_in[2];
  const float* Wk   = (const float*)d_in[3];
  const float* Wv   = (const float*)d_in[4];
  const float* pw_q = (const float*)d_in[5];
  const float* pw_k = (const float*)d_in[6];
  const float* pw_v = (const float*)d_in[7];
  const float* gq   = (const float*)d_in[8];
  const float* bq   = (const float*)d_in[9];
  const float* gk   = (const float*)d_in[10];
  const float* bk   = (const float*)d_in[11];
  const float* gv   = (const float*)d_in[12];
  const float* bv   = (const float*)d_in[13];
  const float* Wp   = (const float*)d_in[14];
  const float* bp   = (const float*)d_in[15];

  char* ws = (char*)d_ws;
  u16* xb    = (u16*)(ws + 0);            // 12,595,200 B
  u16* wb    = (u16*)(ws + 12595200);     // 4,718,592 B (Wq,Wk,Wv,Wp)
  int* maskn = (int*)(ws + 17313792);
  u16* qkv   = (u16*)(ws + 17346816);     // 3*12,595,200 B
  u16* Qp    = (u16*)(ws + 55132416);
  u16* Kp    = (u16*)(ws + 68108544);
  u16* Vt    = (u16*)(ws + 81084672);
  u16* ctx   = (u16*)(ws + 17346816);     // aliases qkv (free after pooling)

  float* out1 = (float*)d_out;
  float* attn = out1 + (size_t)kM*kC;

  k_conv_x<<<2048, 256, 0, stream>>>(reinterpret_cast<const float4*>(x), xb, (kM*kC)/4);
  k_conv_w<<<dim3(576,4), 256, 0, stream>>>(Wq, Wk, Wv, Wp, wb);
  k_mask<<<1, 256, 0, stream>>>((const unsigned char*)msk, maskn, kM);
  k_gemm128<0><<<dim3(65,18), 256, 0, stream>>>(xb, wb, nullptr, qkv, nullptr);
  k_pool3<<<dim3(kBH*264,3), 256, 0, stream>>>(qkv, pw_q, pw_k, pw_v,
                                               gq, bq, gk, bk, gv, bv, Qp, Kp, Vt);
  k_attn<<<96*65, 256, 0, stream>>>(Qp, Kp, Vt, maskn, attn, ctx);
  k_gemm128<1><<<dim3(65,6), 256, 0, stream>>>(ctx, wb, bp, nullptr, out1);
}